// Round 5
// baseline (183.947 us; speedup 1.0000x reference)
//
#include <hip/hip_runtime.h>
#include <hip/hip_bf16.h>

// LSTM cell, B=8192, IN=1024, H=1024.
// gates[8192,4096] = [x|h_prev] @ [Wf|Wi|Wu|Wo] + b ; fused epilogue -> h_t, c_t.
// Round 5: ONE barrier per K-slot (AITER-style, ~32 MFMA per barrier vs 8
// before). Slot body: {issue 4 DMA for slot s+3; 12 ds_read + 32 MFMA with
// compiler counted-lgkm interleave; vmcnt(8) (publishes slot s+1 cross-wave
// BEFORE the barrier); s_barrier}. Ring-4 of K=32 slots, lead-3, vmcnt never 0.

typedef __attribute__((ext_vector_type(8))) short short8;   // 8 bf16
typedef __attribute__((ext_vector_type(4))) float f32x4;

#define GLOBAL_AS __attribute__((address_space(1)))
#define LDS_AS    __attribute__((address_space(3)))

__device__ __forceinline__ void load_lds16(const void* g, void* l) {
  // 16B/lane global->LDS DMA; LDS dest = wave-uniform base + lane*16 (linear)
  __builtin_amdgcn_global_load_lds((const GLOBAL_AS unsigned int*)g,
                                   (LDS_AS unsigned int*)l, 16, 0, 0);
}

__device__ __forceinline__ unsigned short f2bf(float f) {
  unsigned int u = __float_as_uint(f);
  return (unsigned short)((u + 0x7FFFu + ((u >> 16) & 1u)) >> 16);  // RNE
}
__device__ __forceinline__ float sigf(float x) { return 1.0f / (1.0f + __expf(-x)); }
__device__ __forceinline__ float tanh_fast(float x) {
  return 1.0f - 2.0f / (__expf(2.0f * x) + 1.0f);
}

// ---------------------------------------------------------------------------
// Merged pack kernel:
//  blocks [0, 8192):    A = [x | h_prev] -> bf16 Apk[8192][2048], linear
//  blocks [8192,12288): W^T -> bf16 Wp[4096][2048], Wp[n][k] = W_g[k][n']
// ---------------------------------------------------------------------------
__global__ void pack_kernel(const float* __restrict__ x,
                            const float* __restrict__ h,
                            const float* __restrict__ W0,
                            const float* __restrict__ W1,
                            const float* __restrict__ W2,
                            const float* __restrict__ W3,
                            unsigned short* __restrict__ Apk,
                            unsigned short* __restrict__ Wp) {
  int blk = blockIdx.x;
  if (blk < 8192) {
    int t = blk * 256 + threadIdx.x;
    int row = t >> 8;
    int c   = t & 255;
    int k   = c << 3;
    const float* src = (k < 1024) ? (x + (size_t)row * 1024 + k)
                                  : (h + (size_t)row * 1024 + (k - 1024));
    float4 f0 = ((const float4*)src)[0];
    float4 f1 = ((const float4*)src)[1];
    union { unsigned short us[8]; uint4 v; } u;
    u.us[0] = f2bf(f0.x); u.us[1] = f2bf(f0.y);
    u.us[2] = f2bf(f0.z); u.us[3] = f2bf(f0.w);
    u.us[4] = f2bf(f1.x); u.us[5] = f2bf(f1.y);
    u.us[6] = f2bf(f1.z); u.us[7] = f2bf(f1.w);
    *(uint4*)(Apk + (size_t)row * 2048 + c * 8) = u.v;
  } else {
    int b  = blk - 8192;
    int c  = b & 255;          // k-chunk
    int nb = (b >> 8) & 3;     // n' block
    int g  = b >> 10;          // gate
    const float* Wg = (g == 0) ? W0 : (g == 1) ? W1 : (g == 2) ? W2 : W3;
    int np = nb * 256 + threadIdx.x;
    int kbase = c << 3;
    union { unsigned short us[8]; uint4 v; } u;
#pragma unroll
    for (int j = 0; j < 8; ++j)
      u.us[j] = f2bf(Wg[(size_t)(kbase + j) * 1024 + np]);
    int n = (g << 10) + np;
    *(uint4*)(Wp + (size_t)n * 2048 + c * 8) = u.v;
  }
}

// ---------------------------------------------------------------------------
// GEMM + LSTM epilogue, 1 barrier per K-slot.
// Block: 512 thr = 8 waves (2M x 4N). Tile: 256 M x 256 packed cols
// (packed col p = (h>>4)*64 + g*16 + (h&15) -> wave holds 4 gates of same h).
// K=2048 -> 64 slots of K=32; LDS ring of 4 slots (A 16KB + B 16KB each),
// 128 KB dynamic LDS. Per slot per wave: 4 DMA + 12 ds_read_b128 + 32 MFMA.
// ---------------------------------------------------------------------------
#define MFMA16(va, vb, vc) __builtin_amdgcn_mfma_f32_16x16x32_bf16(va, vb, vc, 0, 0, 0)

__global__ __launch_bounds__(512, 2) void lstm_gemm_kernel(
    const unsigned short* __restrict__ Apk,   // [8192][2048] bf16
    const unsigned short* __restrict__ Wp,    // [4096][2048] bf16 (W^T)
    const float* __restrict__ c_prev,
    const float* __restrict__ bF, const float* __restrict__ bI,
    const float* __restrict__ bU, const float* __restrict__ bO,
    float* __restrict__ outH, float* __restrict__ outC) {
  extern __shared__ unsigned short LDSu[];    // 65536 ushorts = 128 KB

  const int tid = threadIdx.x;
  const int l   = tid & 63;
  const int wv  = tid >> 6;        // wave 0..7
  const int wr  = wv >> 2;         // wave M index 0..1
  const int wc  = wv & 3;          // wave N index 0..3

  // XCD-bijective swizzle: 512 blocks = 8 XCDs x 64
  int bid = blockIdx.x;
  int wg  = ((bid & 7) << 6) | (bid >> 3);
  const int mblk = wg >> 4;        // 0..31
  const int nblk = wg & 15;        // 0..15
  const int brow = mblk << 8;      // M base (x256)

  // --- ds_read addressing (ushort units). Rows are 32 us (=64B, one K-slot).
  // swizzled chunk sc = cg ^ ((row>>1)&3); 2-way bank aliasing only (free).
  const int rl  = l & 15;
  const int cg  = l >> 4;                       // k-chunk group 0..3
  const int sc  = cg ^ ((rl >> 1) & 3);
  const int aRdBase = (wr * 128 + rl) * 32 + sc * 8;
  const int bRdBase = (wc * 64 + rl) * 32 + sc * 8;

  // --- staging source addressing: LDS row = qq*128 + wv*16 + (l>>2), linear
  // dest; global source chunk = (l&3) ^ ((ldsrow>>1)&3) = (l&3)^((l>>3)&3).
  const int srow = wv * 16 + (l >> 2);          // 0..127 (qq=0 half)
  const int csw  = ((l & 3) ^ ((l >> 3) & 3)) * 8;
  const unsigned short* aSrc0 = Apk + (size_t)(brow + srow) * 2048 + csw;
  const unsigned short* aSrc1 = aSrc0 + (size_t)128 * 2048;
  // B: LDS row j <-> packed col p = nblk*256 + j ; decode to Wp row n
  int p0 = nblk * 256 + srow;
  int n0 = (((p0 >> 4) & 3) << 10) | ((p0 >> 6) << 4) | (p0 & 15);
  int p1 = p0 + 128;
  int n1 = (((p1 >> 4) & 3) << 10) | ((p1 >> 6) << 4) | (p1 & 15);
  const unsigned short* bSrc0 = Wp + (size_t)n0 * 2048 + csw;
  const unsigned short* bSrc1 = Wp + (size_t)n1 * 2048 + csw;

  f32x4 acc[8][4];                 // [m-frag][gate]
#pragma unroll
  for (int m = 0; m < 8; ++m)
#pragma unroll
    for (int g = 0; g < 4; ++g) acc[m][g] = (f32x4)0.0f;

  // --- prologue: stage slots 0,1,2 into rings 0,1,2 (12 DMA)
#pragma unroll
  for (int s = 0; s < 3; ++s) {
    const int pb = s * 8192;
    const int so = s * 32;
    load_lds16(aSrc0 + so, &LDSu[pb + wv * 512]);
    load_lds16(aSrc1 + so, &LDSu[pb + 4096 + wv * 512]);
    load_lds16(bSrc0 + so, &LDSu[32768 + pb + wv * 512]);
    load_lds16(bSrc1 + so, &LDSu[32768 + pb + 4096 + wv * 512]);
  }
  asm volatile("s_waitcnt vmcnt(8)");   // slot 0 landed (12 issued, 8 after it)
  __builtin_amdgcn_s_barrier();

  // --- main loop: one slot (K=32) per iteration, ONE barrier per slot.
#pragma unroll 1
  for (int s = 0; s < 64; ++s) {
    const int ring  = (s & 3) * 8192;
    const int pring = ((s + 3) & 3) * 8192;
    int sp = s + 3; sp = sp > 63 ? 63 : sp;    // clamp: tail restages slot 63
    const int so = sp * 32;
    // stage slot s+3 (ring (s+3)&3; its last reader finished at barrier s-1)
    load_lds16(aSrc0 + so, &LDSu[pring + wv * 512]);
    load_lds16(aSrc1 + so, &LDSu[pring + 4096 + wv * 512]);
    load_lds16(bSrc0 + so, &LDSu[32768 + pring + wv * 512]);
    load_lds16(bSrc1 + so, &LDSu[32768 + pring + 4096 + wv * 512]);

    // 12 ds_read_b128 (B first so MFMAs can start after 5 reads) + 32 MFMA;
    // compiler interleaves with counted lgkmcnt.
    short8 bfr[4], afr[8];
#pragma unroll
    for (int g = 0; g < 4; ++g)
      bfr[g] = *(const short8*)&LDSu[32768 + ring + bRdBase + g * 512];
#pragma unroll
    for (int m = 0; m < 8; ++m)
      afr[m] = *(const short8*)&LDSu[ring + aRdBase + m * 512];

    __builtin_amdgcn_s_setprio(1);
#pragma unroll
    for (int m = 0; m < 8; ++m)
#pragma unroll
      for (int g = 0; g < 4; ++g)
        acc[m][g] = MFMA16(afr[m], bfr[g], acc[m][g]);
    __builtin_amdgcn_s_setprio(0);

    // publish slot s+1 (its 4 DMAs have 8 issued after them) BEFORE barrier
    asm volatile("s_waitcnt vmcnt(8)");
    __builtin_amdgcn_s_barrier();
  }

  // --- epilogue (register-local LSTM): frag g == gate g for the same h-col.
  const int colh = nblk * 64 + wc * 16 + rl;
  const float biasF = bF[colh], biasI = bI[colh];
  const float biasU = bU[colh], biasO = bO[colh];
  const int row0 = brow + wr * 128 + ((l >> 4) << 2);
#pragma unroll
  for (int m = 0; m < 8; ++m) {
#pragma unroll
    for (int r = 0; r < 4; ++r) {
      int row = row0 + m * 16 + r;
      size_t idx = (size_t)row * 1024 + colh;
      float f  = sigf(acc[m][0][r] + biasF);
      float i_ = sigf(acc[m][1][r] + biasI);
      float g_ = tanh_fast(acc[m][2][r] + biasU);
      float o_ = sigf(acc[m][3][r] + biasO);
      float cp = c_prev[idx];
      float cn = cp * f + i_ * g_;
      outH[idx] = o_ * tanh_fast(cn);
      outC[idx] = cn;
    }
  }
}

// ---------------------------------------------------------------------------
extern "C" void kernel_launch(void* const* d_in, const int* in_sizes, int n_in,
                              void* d_out, int out_size, void* d_ws, size_t ws_size,
                              hipStream_t stream) {
  const float* x      = (const float*)d_in[0];
  const float* h_prev = (const float*)d_in[1];
  const float* c_prev = (const float*)d_in[2];
  // d_in[3] = embed (unused by reference forward)
  const float* Wf = (const float*)d_in[4];
  const float* bf = (const float*)d_in[5];
  const float* Wi = (const float*)d_in[6];
  const float* bi = (const float*)d_in[7];
  const float* Wu = (const float*)d_in[8];
  const float* bu = (const float*)d_in[9];
  const float* Wo = (const float*)d_in[10];
  const float* bo = (const float*)d_in[11];

  unsigned short* Apk = (unsigned short*)d_ws;                                    // 32 MB
  unsigned short* Wp  = (unsigned short*)((char*)d_ws + (size_t)8192 * 2048 * 2); // 16 MB

  pack_kernel<<<12288, 256, 0, stream>>>(x, h_prev, Wf, Wi, Wu, Wo, Apk, Wp);

  // 128 KB dynamic LDS (above the 64 KB default cap)
  hipFuncSetAttribute((const void*)lstm_gemm_kernel,
                      hipFuncAttributeMaxDynamicSharedMemorySize, 131072);

  float* outH = (float*)d_out;
  float* outC = outH + (size_t)8192 * 1024;
  lstm_gemm_kernel<<<512, 512, 131072, stream>>>(Apk, Wp, c_prev,
                                                 bf, bi, bu, bo, outH, outC);
}